// Round 1
// baseline (679.136 us; speedup 1.0000x reference)
//
#include <hip/hip_runtime.h>
#include <math.h>

#define Bsz 256
#define T   512
#define Dd  8
#define Hh  120
#define Ll  4
#define NHn 8
#define HDd 15
#define EPSf 1e-5f

__device__ __forceinline__ float tanh_fast(float x) {
    float e = __expf(2.f * x);
    return 1.f - 2.f / (e + 1.f);
}

// Block = 512 threads = 4 groups of 128 (one per layer), pipelined over ticks.
__global__ __launch_bounds__(512) void slstm_kernel(
    const float* __restrict__ x,
    const float* __restrict__ Wi, const float* __restrict__ Wf,
    const float* __restrict__ Wz, const float* __restrict__ Wo,
    const float* __restrict__ Ri, const float* __restrict__ Rf,
    const float* __restrict__ Rz, const float* __restrict__ Ro,
    const float* __restrict__ bi, const float* __restrict__ bf,
    const float* __restrict__ bz, const float* __restrict__ bo,
    const float* __restrict__ Wp, const float* __restrict__ bp,
    float* __restrict__ last_out)   // [Bsz][Dd]
{
    __shared__ float xs[T * Dd];          // 16 KB, in-place residual stream
    __shared__ float hbuf[Ll][2][Hh];     // double-buffered h per layer
    __shared__ float wp_s[Ll][Dd * Hh];   // Wp per layer
    __shared__ float red[Ll][64];         // projection partials
    __shared__ float bp_s[Ll][Dd];

    const int tid = threadIdx.x;
    const int b   = blockIdx.x;
    const int l   = tid >> 7;    // layer group 0..3
    const int j   = tid & 127;   // lane within group

    // ---- prologue: stage x, zero h, stage Wp/bp ----
    for (int i = tid; i < T * Dd; i += 512) xs[i] = x[b * T * Dd + i];
    for (int i = tid; i < Ll * 2 * Hh; i += 512) ((float*)hbuf)[i] = 0.f;
    for (int i = j; i < Dd * Hh; i += 128) wp_s[l][i] = Wp[l * Dd * Hh + i];
    if (j < Dd) bp_s[l][j] = bp[l * Dd + j];

    // ---- per-thread weights in registers ----
    float wI[Dd], wF[Dd], wZ[Dd], wO[Dd];
    float rI[HDd], rF[HDd], rZ[HDd], rO[HDd];
    float bI = 0.f, bF = 0.f, bZ = 0.f, bO = 0.f;
    int n = 0;
    if (j < Hh) {
        n = j / HDd;
        const int e = j % HDd;
#pragma unroll
        for (int d = 0; d < Dd; ++d) {
            wI[d] = Wi[(l * Hh + j) * Dd + d];
            wF[d] = Wf[(l * Hh + j) * Dd + d];
            wZ[d] = Wz[(l * Hh + j) * Dd + d];
            wO[d] = Wo[(l * Hh + j) * Dd + d];
        }
#pragma unroll
        for (int d = 0; d < HDd; ++d) {
            rI[d] = Ri[((l * NHn + n) * HDd + d) * HDd + e];
            rF[d] = Rf[((l * NHn + n) * HDd + d) * HDd + e];
            rZ[d] = Rz[((l * NHn + n) * HDd + d) * HDd + e];
            rO[d] = Ro[((l * NHn + n) * HDd + d) * HDd + e];
        }
        bI = bi[l * Hh + j]; bF = bf[l * Hh + j];
        bZ = bz[l * Hh + j]; bO = bo[l * Hh + j];
    }

    float c = 0.f, nacc = 0.f, m = 0.f;

    __syncthreads();

    // ---- pipelined recurrence: tick tau, layer l works on t = tau - l ----
    for (int tau = 0; tau < T + Ll - 1; ++tau) {
        const int t = tau - l;
        const bool active = (t >= 0) & (t < T);

        if (active & (j < Hh)) {
            const float* xt = &xs[t * Dd];
            float gi = bI, gf = bF, gz = bZ, go = bO;
#pragma unroll
            for (int d = 0; d < Dd; ++d) {
                const float xv = xt[d];
                gi += xv * wI[d]; gf += xv * wF[d];
                gz += xv * wZ[d]; go += xv * wO[d];
            }
            const float* hh = &hbuf[l][t & 1][n * HDd];
#pragma unroll
            for (int d = 0; d < HDd; ++d) {
                const float hv = hh[d];
                gi += hv * rI[d]; gf += hv * rF[d];
                gz += hv * rZ[d]; go += hv * rO[d];
            }
            const float z  = tanh_fast(gz);
            const float o  = 1.f / (1.f + __expf(-go));
            const float mn = fmaxf(gf + m, gi);
            const float ip = __expf(gi - mn);
            const float fp = __expf(gf + m - mn);
            c    = fp * c + ip * z;
            nacc = fp * nacc + ip;
            m    = mn;
            const float hnew = o * (c / nacc);
            hbuf[l][1 - (t & 1)][j] = hnew;
        }
        __syncthreads();   // h_new visible to projection

        if (active & (j < 64)) {
            const int d = j & 7, chunk = j >> 3;
            const float* hn = hbuf[l][1 - (t & 1)];
            const float* wr = &wp_s[l][d * Hh + chunk * HDd];
            const float* hr = &hn[chunk * HDd];
            float s = 0.f;
#pragma unroll
            for (int k = 0; k < HDd; ++k) s += hr[k] * wr[k];
            red[l][j] = s;
        }
        __syncthreads();   // partials visible

        if (active & (j < Dd)) {
            float y = bp_s[l][j];
#pragma unroll
            for (int cch = 0; cch < 8; ++cch) y += red[l][cch * 8 + j];
            xs[t * Dd + j] += y;   // residual, in-place -> next layer's input
        }
        __syncthreads();   // x update visible to layer l+1 next tick
    }

    if (tid < Dd) last_out[b * Dd + tid] = xs[(T - 1) * Dd + tid];
}

// One block of Bsz threads: batch-norm over batch + FC + sigmoid.
__global__ __launch_bounds__(Bsz) void bn_fc_kernel(
    const float* __restrict__ last,   // [Bsz][Dd]
    const float* __restrict__ gamma, const float* __restrict__ beta,
    const float* __restrict__ Wfc,   const float* __restrict__ bfc,
    float* __restrict__ out)          // [Bsz]
{
    __shared__ float ls[Bsz][Dd];
    __shared__ float mu[Dd], rstdg[Dd], bet[Dd], wfc[Dd];
    const int tid = threadIdx.x;
#pragma unroll
    for (int d = 0; d < Dd; ++d) ls[tid][d] = last[tid * Dd + d];
    __syncthreads();
    if (tid < Dd) {
        float s = 0.f;
        for (int bb = 0; bb < Bsz; ++bb) s += ls[bb][tid];
        const float mean = s * (1.f / Bsz);
        float v = 0.f;
        for (int bb = 0; bb < Bsz; ++bb) {
            const float dd = ls[bb][tid] - mean;
            v += dd * dd;
        }
        v *= (1.f / Bsz);
        mu[tid]    = mean;
        rstdg[tid] = rsqrtf(v + EPSf) * gamma[tid];
        bet[tid]   = beta[tid];
        wfc[tid]   = Wfc[tid];
    }
    __syncthreads();
    float acc = bfc[0];
#pragma unroll
    for (int d = 0; d < Dd; ++d)
        acc += ((ls[tid][d] - mu[d]) * rstdg[d] + bet[d]) * wfc[d];
    out[tid] = 1.f / (1.f + __expf(-acc));
}

extern "C" void kernel_launch(void* const* d_in, const int* in_sizes, int n_in,
                              void* d_out, int out_size, void* d_ws, size_t ws_size,
                              hipStream_t stream) {
    const float* x    = (const float*)d_in[0];
    const float* Wi   = (const float*)d_in[1];
    const float* Wf   = (const float*)d_in[2];
    const float* Wz   = (const float*)d_in[3];
    const float* Wo   = (const float*)d_in[4];
    const float* Ri   = (const float*)d_in[5];
    const float* Rf   = (const float*)d_in[6];
    const float* Rz   = (const float*)d_in[7];
    const float* Ro   = (const float*)d_in[8];
    const float* bi   = (const float*)d_in[9];
    const float* bf   = (const float*)d_in[10];
    const float* bz   = (const float*)d_in[11];
    const float* bo   = (const float*)d_in[12];
    const float* Wp   = (const float*)d_in[13];
    const float* bp   = (const float*)d_in[14];
    const float* gamma= (const float*)d_in[15];
    const float* beta = (const float*)d_in[16];
    const float* Wfc  = (const float*)d_in[17];
    const float* bfc  = (const float*)d_in[18];

    float* last_ws = (float*)d_ws;          // Bsz*Dd floats = 8 KB
    float* out     = (float*)d_out;         // Bsz floats

    slstm_kernel<<<Bsz, 512, 0, stream>>>(x, Wi, Wf, Wz, Wo, Ri, Rf, Rz, Ro,
                                          bi, bf, bz, bo, Wp, bp, last_ws);
    bn_fc_kernel<<<1, Bsz, 0, stream>>>(last_ws, gamma, beta, Wfc, bfc, out);
}

// Round 2
// 467.980 us; speedup vs baseline: 1.4512x; 1.4512x over previous
//
#include <hip/hip_runtime.h>
#include <math.h>

#define Bsz 256
#define T   512
#define Dd  8
#define Hh  120
#define Ll  4
#define NHn 8
#define HDd 15
#define HP  16      // padded head row (15 -> 16 floats) for b128 LDS reads
#define EPSf 1e-5f

__device__ __forceinline__ float fast_rcp(float x) {
#if __has_builtin(__builtin_amdgcn_rcpf)
    return __builtin_amdgcn_rcpf(x);
#else
    return 1.f / x;
#endif
}
__device__ __forceinline__ float tanh_fast(float x) {
    float e = __expf(2.f * x);
    return 1.f - 2.f * fast_rcp(e + 1.f);
}
__device__ __forceinline__ float sigm_fast(float x) {
    return fast_rcp(1.f + __expf(-x));
}

// Block = 512 threads = 4 layer-groups of 128 (2 waves each), pipelined over
// ticks: layer l works on timestep t = tau - l. Weights live in registers
// (launch_bounds(512,2) -> VGPR cap 256, no spill). 2 barriers per tick.
__global__ __launch_bounds__(512, 2) void slstm_kernel(
    const float* __restrict__ x,
    const float* __restrict__ Wi, const float* __restrict__ Wf,
    const float* __restrict__ Wz, const float* __restrict__ Wo,
    const float* __restrict__ Ri, const float* __restrict__ Rf,
    const float* __restrict__ Rz, const float* __restrict__ Ro,
    const float* __restrict__ bi, const float* __restrict__ bf,
    const float* __restrict__ bz, const float* __restrict__ bo,
    const float* __restrict__ Wp, const float* __restrict__ bp,
    float* __restrict__ last_out)   // [Bsz][Dd]
{
    __shared__ __align__(16) float xs[T * Dd];            // 16 KB residual stream
    __shared__ __align__(16) float hb[Ll][2][NHn * HP];   // 4 KB, padded heads

    const int tid = threadIdx.x;
    const int b   = blockIdx.x;
    const int l   = tid >> 7;    // layer group 0..3
    const int j   = tid & 127;   // lane within group

    // ---- prologue: stage x (float4), zero h ----
    {
        const float4* xg  = (const float4*)(x + (size_t)b * T * Dd);
        float4*       xs4 = (float4*)xs;
        xs4[tid]       = xg[tid];          // T*Dd/4 = 1024 = 2*512
        xs4[tid + 512] = xg[tid + 512];
        ((float*)hb)[tid]       = 0.f;     // Ll*2*NHn*HP = 1024
        ((float*)hb)[tid + 512] = 0.f;
    }

    // ---- per-thread gate weights in registers ----
    const bool gl = (j < Hh);
    int n = 0;
    float wI[Dd], wF[Dd], wZ[Dd], wO[Dd];
    float rI[HDd], rF[HDd], rZ[HDd], rO[HDd];
    float bI = 0.f, bF = 0.f, bZ = 0.f, bO = 0.f;
    if (gl) {
        n = j / HDd;
        const int e   = j - n * HDd;
        const int row = (l * Hh + j) * Dd;
#pragma unroll
        for (int d = 0; d < Dd; ++d) {
            wI[d] = Wi[row + d]; wF[d] = Wf[row + d];
            wZ[d] = Wz[row + d]; wO[d] = Wo[row + d];
        }
        const int rb = ((l * NHn + n) * HDd) * HDd + e;
#pragma unroll
        for (int d = 0; d < HDd; ++d) {
            rI[d] = Ri[rb + d * HDd]; rF[d] = Rf[rb + d * HDd];
            rZ[d] = Rz[rb + d * HDd]; rO[d] = Ro[rb + d * HDd];
        }
        bI = bi[l * Hh + j]; bF = bf[l * Hh + j];
        bZ = bz[l * Hh + j]; bO = bo[l * Hh + j];
    }

    // ---- projection weights (wave 0 of each group) in registers ----
    const int d8 = j & 7, ch = j >> 3;
    float wp_r[HDd];
    float bp_r = 0.f;
    if (j < 64) {
        const int base = l * Dd * Hh + d8 * Hh + ch * HDd;
#pragma unroll
        for (int k = 0; k < HDd; ++k) wp_r[k] = Wp[base + k];
        if (j < Dd) bp_r = bp[l * Dd + j];
    }

    float cst = 0.f, nst = 0.f, mst = 0.f;

    __syncthreads();

    // ---- pipelined recurrence: 2 barriers per tick ----
    for (int tau = 0; tau < T + Ll - 1; ++tau) {
        const int t   = tau - l;
        const bool act = (t >= 0) && (t < T);

        if (act && gl) {
            const float4* xt4 = (const float4*)(xs + t * Dd);
            const float4 xa = xt4[0], xb2 = xt4[1];
            const float xv[Dd] = {xa.x, xa.y, xa.z, xa.w, xb2.x, xb2.y, xb2.z, xb2.w};
            float gi = bI, gf = bF, gz = bZ, go = bO;
#pragma unroll
            for (int d = 0; d < Dd; ++d) {
                gi = fmaf(xv[d], wI[d], gi);
                gf = fmaf(xv[d], wF[d], gf);
                gz = fmaf(xv[d], wZ[d], gz);
                go = fmaf(xv[d], wO[d], go);
            }
            const float4* h4 = (const float4*)(&hb[l][t & 1][n * HP]);
            const float4 h0 = h4[0], h1 = h4[1], h2 = h4[2], h3 = h4[3];
            const float hv[16] = {h0.x, h0.y, h0.z, h0.w, h1.x, h1.y, h1.z, h1.w,
                                  h2.x, h2.y, h2.z, h2.w, h3.x, h3.y, h3.z, h3.w};
#pragma unroll
            for (int d = 0; d < HDd; ++d) {
                gi = fmaf(hv[d], rI[d], gi);
                gf = fmaf(hv[d], rF[d], gf);
                gz = fmaf(hv[d], rZ[d], gz);
                go = fmaf(hv[d], rO[d], go);
            }
            const float z  = tanh_fast(gz);
            const float o  = sigm_fast(go);
            const float mn = fmaxf(gf + mst, gi);
            const float ip = __expf(gi - mn);
            const float fp = __expf(gf + mst - mn);
            cst = fmaf(fp, cst, ip * z);
            nst = fmaf(fp, nst, ip);
            mst = mn;
            const float hnew = o * cst * fast_rcp(nst);
            hb[l][(t & 1) ^ 1][n * HP + (j - n * HDd)] = hnew;
        }
        __syncthreads();   // h_new visible to projection lanes

        if (act && (j < 64)) {
            const float* hn = &hb[l][(t & 1) ^ 1][ch * HP];
            float s = 0.f;
#pragma unroll
            for (int k = 0; k < HDd; ++k) s = fmaf(hn[k], wp_r[k], s);
            // reduce over the 8 chunks (lane bits 3..5)
            s += __shfl_xor(s, 8);
            s += __shfl_xor(s, 16);
            s += __shfl_xor(s, 32);
            if (j < Dd) xs[t * Dd + j] += s + bp_r;   // residual update
        }
        __syncthreads();   // xs visible to layer l+1 next tick
    }

    if (tid < Dd) last_out[b * Dd + tid] = xs[(T - 1) * Dd + tid];
}

// One block of Bsz threads: batch-norm over batch + FC + sigmoid.
__global__ __launch_bounds__(Bsz) void bn_fc_kernel(
    const float* __restrict__ last,   // [Bsz][Dd]
    const float* __restrict__ gamma, const float* __restrict__ beta,
    const float* __restrict__ Wfc,   const float* __restrict__ bfc,
    float* __restrict__ out)          // [Bsz]
{
    __shared__ float ls[Bsz][Dd];
    __shared__ float mu[Dd], rstdg[Dd], bet[Dd], wfc[Dd];
    const int tid = threadIdx.x;
#pragma unroll
    for (int d = 0; d < Dd; ++d) ls[tid][d] = last[tid * Dd + d];
    __syncthreads();
    if (tid < Dd) {
        float s = 0.f;
        for (int bb = 0; bb < Bsz; ++bb) s += ls[bb][tid];
        const float mean = s * (1.f / Bsz);
        float v = 0.f;
        for (int bb = 0; bb < Bsz; ++bb) {
            const float dd = ls[bb][tid] - mean;
            v += dd * dd;
        }
        v *= (1.f / Bsz);
        mu[tid]    = mean;
        rstdg[tid] = rsqrtf(v + EPSf) * gamma[tid];
        bet[tid]   = beta[tid];
        wfc[tid]   = Wfc[tid];
    }
    __syncthreads();
    float acc = bfc[0];
#pragma unroll
    for (int d = 0; d < Dd; ++d)
        acc += ((ls[tid][d] - mu[d]) * rstdg[d] + bet[d]) * wfc[d];
    out[tid] = sigm_fast(acc);
}

extern "C" void kernel_launch(void* const* d_in, const int* in_sizes, int n_in,
                              void* d_out, int out_size, void* d_ws, size_t ws_size,
                              hipStream_t stream) {
    const float* x    = (const float*)d_in[0];
    const float* Wi   = (const float*)d_in[1];
    const float* Wf   = (const float*)d_in[2];
    const float* Wz   = (const float*)d_in[3];
    const float* Wo   = (const float*)d_in[4];
    const float* Ri   = (const float*)d_in[5];
    const float* Rf   = (const float*)d_in[6];
    const float* Rz   = (const float*)d_in[7];
    const float* Ro   = (const float*)d_in[8];
    const float* bi   = (const float*)d_in[9];
    const float* bf   = (const float*)d_in[10];
    const float* bz   = (const float*)d_in[11];
    const float* bo   = (const float*)d_in[12];
    const float* Wp   = (const float*)d_in[13];
    const float* bp   = (const float*)d_in[14];
    const float* gamma= (const float*)d_in[15];
    const float* beta = (const float*)d_in[16];
    const float* Wfc  = (const float*)d_in[17];
    const float* bfc  = (const float*)d_in[18];

    float* last_ws = (float*)d_ws;          // Bsz*Dd floats
    float* out     = (float*)d_out;         // Bsz floats

    slstm_kernel<<<Bsz, 512, 0, stream>>>(x, Wi, Wf, Wz, Wo, Ri, Rf, Rz, Ro,
                                          bi, bf, bz, bo, Wp, bp, last_ws);
    bn_fc_kernel<<<1, Bsz, 0, stream>>>(last_ws, gamma, beta, Wfc, bfc, out);
}

// Round 3
// 453.119 us; speedup vs baseline: 1.4988x; 1.0328x over previous
//
#include <hip/hip_runtime.h>
#include <math.h>

#define Bsz 256
#define T   512
#define Dd  8
#define Hh  120
#define Ll  4
#define NHn 8
#define HDd 15
#define HP  16      // padded head row (15 -> 16 floats) for b128 LDS reads
#define EPSf 1e-5f

__device__ __forceinline__ float fast_rcp(float x) {
#if __has_builtin(__builtin_amdgcn_rcpf)
    return __builtin_amdgcn_rcpf(x);
#else
    return 1.f / x;
#endif
}
__device__ __forceinline__ float tanh_fast(float x) {
    float e = __expf(2.f * x);
    return 1.f - 2.f * fast_rcp(e + 1.f);
}
__device__ __forceinline__ float sigm_fast(float x) {
    return fast_rcp(1.f + __expf(-x));
}

// Block = 512 threads = 4 layer-groups of 128 (2 waves each).
// Pipeline skew: layer l computes gates for t_g = tau - 2l, and the
// projection of h(t_p = tau - 2l - 1) in the SAME tick on wave 1 of the
// group. Parity: gate xs-reads are at even (tau-2l) offsets, projection
// xs-writes at odd -> never the same element in one tick -> ONE barrier/tick.
__global__ __launch_bounds__(512, 2) void slstm_kernel(
    const float* __restrict__ x,
    const float* __restrict__ Wi, const float* __restrict__ Wf,
    const float* __restrict__ Wz, const float* __restrict__ Wo,
    const float* __restrict__ Ri, const float* __restrict__ Rf,
    const float* __restrict__ Rz, const float* __restrict__ Ro,
    const float* __restrict__ bi, const float* __restrict__ bf,
    const float* __restrict__ bz, const float* __restrict__ bo,
    const float* __restrict__ Wp, const float* __restrict__ bp,
    float* __restrict__ last_out)   // [Bsz][Dd]
{
    __shared__ __align__(16) float xs[T * Dd];            // 16 KB residual stream
    __shared__ __align__(16) float hb[Ll][2][NHn * HP];   // 4 KB, padded heads

    const int tid = threadIdx.x;
    const int b   = blockIdx.x;
    const int l   = tid >> 7;    // layer group 0..3
    const int j   = tid & 127;   // lane within group

    // ---- prologue: stage x (float4), zero h ----
    {
        const float4* xg  = (const float4*)(x + (size_t)b * T * Dd);
        float4*       xs4 = (float4*)xs;
        xs4[tid]       = xg[tid];          // T*Dd/4 = 1024 = 2*512
        xs4[tid + 512] = xg[tid + 512];
        ((float*)hb)[tid]       = 0.f;     // Ll*2*NHn*HP = 1024
        ((float*)hb)[tid + 512] = 0.f;
    }

    // ---- per-thread gate weights -> registers (unconditional, clamped) ----
    const bool gl = (j < Hh);
    const int jj  = gl ? j : 0;
    const int n   = jj / HDd;
    const int e   = jj - n * HDd;
    float wI[Dd], wF[Dd], wZ[Dd], wO[Dd];
    float rI[HDd], rF[HDd], rZ[HDd], rO[HDd];
    {
        const int row = (l * Hh + jj) * Dd;
#pragma unroll
        for (int d = 0; d < Dd; ++d) {
            wI[d] = Wi[row + d]; wF[d] = Wf[row + d];
            wZ[d] = Wz[row + d]; wO[d] = Wo[row + d];
        }
        const int rb = ((l * NHn + n) * HDd) * HDd + e;
#pragma unroll
        for (int d = 0; d < HDd; ++d) {
            rI[d] = Ri[rb + d * HDd]; rF[d] = Rf[rb + d * HDd];
            rZ[d] = Rz[rb + d * HDd]; rO[d] = Ro[rb + d * HDd];
        }
    }
    float bI = bi[l * Hh + jj], bF = bf[l * Hh + jj];
    float bZ = bz[l * Hh + jj], bO = bo[l * Hh + jj];

    // ---- projection weights (used by wave 1; loaded by all, clamped) ----
    const int p  = (j >= 64) ? (j - 64) : j;   // lane within wave 1
    const int d8 = p & 7, ch = p >> 3;
    float wp_r[16];
    {
        const int base = l * Dd * Hh + d8 * Hh + ch * HDd;
#pragma unroll
        for (int k = 0; k < HDd; ++k) wp_r[k] = Wp[base + k];
        wp_r[15] = 0.f;                        // pairs with hb pad slot (==0)
    }
    float bp_r = bp[l * Dd + d8];

    // ---- pin everything in VGPRs: forbid rematerialization in the loop ----
#pragma unroll
    for (int d = 0; d < Dd; ++d)
        asm volatile("" : "+v"(wI[d]), "+v"(wF[d]), "+v"(wZ[d]), "+v"(wO[d]));
#pragma unroll
    for (int d = 0; d < HDd; ++d)
        asm volatile("" : "+v"(rI[d]), "+v"(rF[d]), "+v"(rZ[d]), "+v"(rO[d]));
#pragma unroll
    for (int k = 0; k < 16; ++k)
        asm volatile("" : "+v"(wp_r[k]));
    asm volatile("" : "+v"(bI), "+v"(bF), "+v"(bZ), "+v"(bO));
    asm volatile("" : "+v"(bp_r));

    float cst = 0.f, nst = 0.f, mst = 0.f;

    __syncthreads();

    // ---- pipelined recurrence: ONE barrier per tick ----
    for (int tau = 0; tau < T + 2 * Ll - 1; ++tau) {
        const int t_g = tau - 2 * l;       // gate timestep
        const int t_p = t_g - 1;           // projection timestep

        // gates: read xs[t_g] + h(t_g-1), write h(t_g)
        if (gl && (t_g >= 0) && (t_g < T)) {
            const float4* xt4 = (const float4*)(xs + t_g * Dd);
            const float4 xa = xt4[0], xb2 = xt4[1];
            const float xv[Dd] = {xa.x, xa.y, xa.z, xa.w, xb2.x, xb2.y, xb2.z, xb2.w};
            float gi = bI, gf = bF, gz = bZ, go = bO;
#pragma unroll
            for (int d = 0; d < Dd; ++d) {
                gi = fmaf(xv[d], wI[d], gi);
                gf = fmaf(xv[d], wF[d], gf);
                gz = fmaf(xv[d], wZ[d], gz);
                go = fmaf(xv[d], wO[d], go);
            }
            const float4* h4 = (const float4*)(&hb[l][t_g & 1][n * HP]);
            const float4 h0 = h4[0], h1 = h4[1], h2 = h4[2], h3 = h4[3];
            const float hv[16] = {h0.x, h0.y, h0.z, h0.w, h1.x, h1.y, h1.z, h1.w,
                                  h2.x, h2.y, h2.z, h2.w, h3.x, h3.y, h3.z, h3.w};
#pragma unroll
            for (int d = 0; d < HDd; ++d) {
                gi = fmaf(hv[d], rI[d], gi);
                gf = fmaf(hv[d], rF[d], gf);
                gz = fmaf(hv[d], rZ[d], gz);
                go = fmaf(hv[d], rO[d], go);
            }
            const float z  = tanh_fast(gz);
            const float o  = sigm_fast(go);
            const float mn = fmaxf(gf + mst, gi);
            const float ip = __expf(gi - mn);
            const float fp = __expf(gf + mst - mn);
            cst = fmaf(fp, cst, ip * z);
            nst = fmaf(fp, nst, ip);
            mst = mn;
            const float hnew = o * cst * fast_rcp(nst);
            hb[l][(t_g & 1) ^ 1][n * HP + e] = hnew;
        }

        // projection of h(t_p) (wave 1 of the group), residual into xs[t_p]
        if ((j >= 64) && (t_p >= 0) && (t_p < T)) {
            // h(t_p) lives in buffer (t_p&1)^1 == t_g&1
            const float4* h4 = (const float4*)(&hb[l][t_g & 1][ch * HP]);
            const float4 h0 = h4[0], h1 = h4[1], h2 = h4[2], h3 = h4[3];
            const float hv[16] = {h0.x, h0.y, h0.z, h0.w, h1.x, h1.y, h1.z, h1.w,
                                  h2.x, h2.y, h2.z, h2.w, h3.x, h3.y, h3.z, h3.w};
            float s = 0.f;
#pragma unroll
            for (int k = 0; k < 16; ++k) s = fmaf(hv[k], wp_r[k], s);
            // reduce over the 8 chunks (lane bits 3..5 within wave 1)
            s += __shfl_xor(s, 8);
            s += __shfl_xor(s, 16);
            s += __shfl_xor(s, 32);
            if (p < Dd) xs[t_p * Dd + p] += s + bp_r;   // residual update
        }

        __syncthreads();
    }

    if (tid < Dd) last_out[b * Dd + tid] = xs[(T - 1) * Dd + tid];
}

// One block of Bsz threads: batch-norm over batch + FC + sigmoid.
__global__ __launch_bounds__(Bsz) void bn_fc_kernel(
    const float* __restrict__ last,   // [Bsz][Dd]
    const float* __restrict__ gamma, const float* __restrict__ beta,
    const float* __restrict__ Wfc,   const float* __restrict__ bfc,
    float* __restrict__ out)          // [Bsz]
{
    __shared__ float ls[Bsz][Dd];
    __shared__ float mu[Dd], rstdg[Dd], bet[Dd], wfc[Dd];
    const int tid = threadIdx.x;
#pragma unroll
    for (int d = 0; d < Dd; ++d) ls[tid][d] = last[tid * Dd + d];
    __syncthreads();
    if (tid < Dd) {
        float s = 0.f;
        for (int bb = 0; bb < Bsz; ++bb) s += ls[bb][tid];
        const float mean = s * (1.f / Bsz);
        float v = 0.f;
        for (int bb = 0; bb < Bsz; ++bb) {
            const float dd = ls[bb][tid] - mean;
            v += dd * dd;
        }
        v *= (1.f / Bsz);
        mu[tid]    = mean;
        rstdg[tid] = rsqrtf(v + EPSf) * gamma[tid];
        bet[tid]   = beta[tid];
        wfc[tid]   = Wfc[tid];
    }
    __syncthreads();
    float acc = bfc[0];
#pragma unroll
    for (int d = 0; d < Dd; ++d)
        acc += ((ls[tid][d] - mu[d]) * rstdg[d] + bet[d]) * wfc[d];
    out[tid] = sigm_fast(acc);
}

extern "C" void kernel_launch(void* const* d_in, const int* in_sizes, int n_in,
                              void* d_out, int out_size, void* d_ws, size_t ws_size,
                              hipStream_t stream) {
    const float* x    = (const float*)d_in[0];
    const float* Wi   = (const float*)d_in[1];
    const float* Wf   = (const float*)d_in[2];
    const float* Wz   = (const float*)d_in[3];
    const float* Wo   = (const float*)d_in[4];
    const float* Ri   = (const float*)d_in[5];
    const float* Rf   = (const float*)d_in[6];
    const float* Rz   = (const float*)d_in[7];
    const float* Ro   = (const float*)d_in[8];
    const float* bi   = (const float*)d_in[9];
    const float* bf   = (const float*)d_in[10];
    const float* bz   = (const float*)d_in[11];
    const float* bo   = (const float*)d_in[12];
    const float* Wp   = (const float*)d_in[13];
    const float* bp   = (const float*)d_in[14];
    const float* gamma= (const float*)d_in[15];
    const float* beta = (const float*)d_in[16];
    const float* Wfc  = (const float*)d_in[17];
    const float* bfc  = (const float*)d_in[18];

    float* last_ws = (float*)d_ws;          // Bsz*Dd floats
    float* out     = (float*)d_out;         // Bsz floats

    slstm_kernel<<<Bsz, 512, 0, stream>>>(x, Wi, Wf, Wz, Wo, Ri, Rf, Rz, Ro,
                                          bi, bf, bz, bo, Wp, bp, last_ws);
    bn_fc_kernel<<<1, Bsz, 0, stream>>>(last_ws, gamma, beta, Wfc, bfc, out);
}